// Round 13
// baseline (4904.840 us; speedup 1.0000x reference)
//
#include <hip/hip_runtime.h>

// LSTM on MI355X — persistent kernel, round 12.
// Base = R11 (4329us). ONE mechanism change: detection topology collapsed from
// {256 flags -> block0/w4 aggregator scan -> 8 epoch replicas -> consumer poll}
// to {256 relaxed agent atomic_fetch_add on ONE counter -> consumer poll}.
// Deletes two serial MALL links (aggregator detect + epoch store). Relaxed RMWs
// do no cache maintenance (unlike R1/R2's acq_rel+fence storm). Aggregator wave
// deleted -> 256 threads/block. Data ordering unchanged: sc0sc1 drain BEFORE
// the add; cached write-once-ring reads fresh-by-construction (R9-proven).
// Everything else byte-identical to R11. absmax canary: 0.001953125.

namespace {
constexpr int T_STEPS = 512;
constexpr int BATCH   = 64;
constexpr int DI      = 512;
constexpr int DL      = 1024;
constexpr int NKC     = 48;   // K=1536 in chunks of 32
constexpr int NKC_H   = 32;   // h-part chunks (K=1024)
constexpr int NBLK    = 256;  // grid == CU count, 1 block/CU resident
constexpr int NTHR    = 256;  // 4 compute waves (aggregator wave deleted)
constexpr int FPAD    = 32;   // uints per slot (128 B padding)
}

typedef __attribute__((ext_vector_type(8))) short bf16x8;
typedef __attribute__((ext_vector_type(8))) unsigned short u16x8;
typedef __attribute__((ext_vector_type(4))) float f32x4;
typedef __attribute__((ext_vector_type(4))) unsigned int u32x4;
typedef __attribute__((ext_vector_type(2))) unsigned int u32x2;

__device__ __forceinline__ unsigned short f2bf(float x){
  unsigned int u = __float_as_uint(x);
  return (unsigned short)((u + 0x7FFFu + ((u >> 16) & 1u)) >> 16);
}
__device__ __forceinline__ float bf2f(unsigned short b){
  return __uint_as_float(((unsigned int)b) << 16);
}
__device__ __forceinline__ float fast_sigmoid(float v){
  return __fdividef(1.f, 1.f + __expf(-v));
}
__device__ __forceinline__ float fast_tanh(float v){
  v = fminf(fmaxf(v, -15.f), 15.f);
  float t = __expf(2.f * v);
  return __fdividef(t - 1.f, t + 1.f);
}

// ---------------- prep: embeddings -> bf16 [T*B][DI] ----------------
__global__ void prep_xe(const int* __restrict__ X, const float* __restrict__ emb,
                        unsigned short* __restrict__ xe){
  int i = blockIdx.x * blockDim.x + threadIdx.x;
  const int total = T_STEPS * BATCH * DI / 8;
  if (i >= total) return;
  int row = i >> 6;
  int seg = i & 63;
  int tok = X[row];
  const float* src = emb + (long long)tok * DI + seg * 8;
  float4 v0 = *(const float4*)src;
  float4 v1 = *(const float4*)(src + 4);
  u16x8 o;
  o[0]=f2bf(v0.x); o[1]=f2bf(v0.y); o[2]=f2bf(v0.z); o[3]=f2bf(v0.w);
  o[4]=f2bf(v1.x); o[5]=f2bf(v1.y); o[6]=f2bf(v1.z); o[7]=f2bf(v1.w);
  *(u16x8*)(xe + (long long)row * DI + seg * 8) = o;
}

// ---------------- prep: pack W into MFMA B-fragment layout, hi/lo ----------------
__global__ void prep_w(const float* __restrict__ Wf, const float* __restrict__ Wi,
                       const float* __restrict__ Wc, const float* __restrict__ Wo,
                       unsigned short* __restrict__ W_hi, unsigned short* __restrict__ W_lo){
  int idx = blockIdx.x * blockDim.x + threadIdx.x;
  if (idx >= 256 * NKC * 64) return;
  int lane = idx & 63;
  int kc   = (idx >> 6) % NKC;
  int bk   = idx / (64 * NKC);
  int lc = lane & 15, kg = lane >> 4;
  int g  = lc >> 2;
  int jl = bk * 4 + (lc & 3);
  const float* Wg = (g == 0) ? Wf : ((g == 1) ? Wi : ((g == 2) ? Wc : Wo));
  int kbase = kc * 32 + kg * 8;
  u16x8 hi, lo;
#pragma unroll
  for (int j = 0; j < 8; j++){
    float wv = Wg[(long long)(kbase + j) * DL + jl];
    unsigned short h = f2bf(wv);
    hi[j] = h;
    lo[j] = f2bf(wv - bf2f(h));
  }
  *(u16x8*)(W_hi + ((long long)(bk * NKC + kc) * 64 + lane) * 8) = hi;
  if (kc < NKC_H)
    *(u16x8*)(W_lo + ((long long)(bk * NKC_H + kc) * 64 + lane) * 8) = lo;
}

// ---------------- prep: h0 -> ring slot 0 (bf16), bias pack, counter zero ----------------
__global__ void prep_h(const float* __restrict__ h0,
                       const float* __restrict__ bf_, const float* __restrict__ bi_,
                       const float* __restrict__ bc_, const float* __restrict__ bo_,
                       unsigned short* __restrict__ hRing,
                       float* __restrict__ bias_pack, unsigned int* __restrict__ bar){
  int i = blockIdx.x * blockDim.x + threadIdx.x;
  if (i < BATCH * DL) hRing[i] = f2bf(h0[i]);      // slot 0 = h_0
  if (i < 4096){
    int r = i & 3, g = (i >> 2) & 3, bk = i >> 4;
    const float* bg = (g == 0) ? bf_ : ((g == 1) ? bi_ : ((g == 2) ? bc_ : bo_));
    bias_pack[i] = bg[bk * 4 + r];
  }
  if (i < 8 * FPAD) bar[i] = 0u;                   // counter line (+ padding)
}

// ---------------- persistent LSTM: all 512 steps in one kernel ----------------
// CACHED=true : ring depth T+1 (write-once), consumer loads plain cached.
// CACHED=false: ring depth 2 (double buffer),  consumer loads sc0 sc1 (=R6).
template<bool CACHED>
__launch_bounds__(NTHR, 1)
__global__ void lstm_persist(const unsigned short* __restrict__ xe,
                             const unsigned short* __restrict__ W_hi,
                             const unsigned short* __restrict__ W_lo,
                             unsigned short* __restrict__ hRing,
                             const float* __restrict__ bias_pack,
                             float* __restrict__ out,
                             unsigned int* __restrict__ bar){
  extern __shared__ unsigned short lds[];
  unsigned short* lds_hi = lds;              // NKC  *512 elems (48 KB)
  unsigned short* lds_lo = lds + NKC * 512;  // NKC_H*512 elems (32 KB)
  __shared__ unsigned short stage_h[BATCH * 4];  // bf16 h slice [64 rows][4 cols]
  __shared__ float          stage_o[BATCH * 4];  // out slice
  const int tid  = threadIdx.x;
  const int bk   = blockIdx.x;
  const int w    = tid >> 6;
  const int lane = tid & 63;

  // stage W once for the whole run
  const uint4* srcHi = (const uint4*)(W_hi + (size_t)bk * NKC * 512);
  uint4* dHi = (uint4*)lds_hi;
  for (int i = tid; i < 3072; i += NTHR) dHi[i] = srcHi[i];
  const uint4* srcLo = (const uint4*)(W_lo + (size_t)bk * NKC_H * 512);
  uint4* dLo = (uint4*)lds_lo;
  for (int i = tid; i < 2048; i += NTHR) dLo[i] = srcLo[i];
  __syncthreads();

  const int lc = lane & 15;
  const int kg = lane >> 4;
  const int g  = lc >> 2;
  const int rowb = (w << 4) + lc;
  const float bias = bias_pack[bk * 16 + lc];
  const int srcBase = (lane & 48) | (lc & 3);
  const int hOff = rowb * DL + kg * 8;     // u16 elements
  const int xOff = rowb * DI + kg * 8;
  float cr0 = 0.f, cr1 = 0.f, cr2 = 0.f, cr3 = 0.f;

  f32x4 acc0 = {0.f,0.f,0.f,0.f}, acc1 = {0.f,0.f,0.f,0.f};
  f32x4 acc2 = {0.f,0.f,0.f,0.f}, acc3 = {0.f,0.f,0.f,0.f};

#define XSTEP(KC, ACC) {                                                        \
    bf16x8 ax = *(const bf16x8*)(xRow + (KC) * 32);                             \
    bf16x8 bh = *(const bf16x8*)(lds_hi + (NKC_H + (KC)) * 512 + lane * 8);     \
    ACC = __builtin_amdgcn_mfma_f32_16x16x32_bf16(ax, bh, ACC, 0, 0, 0); }
#define HSTEP2(KC, ACC) {                                                       \
    bf16x8 ah = *(const bf16x8*)&hv[KC];                                        \
    bf16x8 bh = *(const bf16x8*)(lds_hi + (KC) * 512 + lane * 8);               \
    bf16x8 bl = *(const bf16x8*)(lds_lo + (KC) * 512 + lane * 8);               \
    ACC = __builtin_amdgcn_mfma_f32_16x16x32_bf16(ah, bh, ACC, 0, 0, 0);        \
    ACC = __builtin_amdgcn_mfma_f32_16x16x32_bf16(ah, bl, ACC, 0, 0, 0); }
#define LOADHC(I, OFFSTR)                                                       \
    asm volatile("global_load_dwordx4 %0, %1, off offset:" OFFSTR               \
                 : "=v"(hv[I]) : "v"(hbase));
#define LOADHU(I, OFFSTR)                                                       \
    asm volatile("global_load_dwordx4 %0, %1, off offset:" OFFSTR " sc0 sc1"    \
                 : "=v"(hv[I]) : "v"(hbase));

  // x-part for step 0
  {
    const unsigned short* xRow = xe + xOff;
#pragma unroll
    for (int kc = 0; kc < 16; kc += 4){
      XSTEP(kc, acc0) XSTEP(kc + 1, acc1) XSTEP(kc + 2, acc2) XSTEP(kc + 3, acc3)
    }
  }

#pragma unroll 1
  for (int t = 0; t < T_STEPS; ++t){
    // ---- wait: counter >= 256*t (all blocks published slot t), w0 polls ----
    if (t > 0 && w == 0){
      const unsigned tgt = (unsigned)NBLK * (unsigned)t;
      int spin = 0;
      while (__hip_atomic_load(bar, __ATOMIC_RELAXED, __HIP_MEMORY_SCOPE_AGENT) < tgt){
        __builtin_amdgcn_s_sleep(1);
        if (++spin > (1 << 16)) break;   // bail loud (absmax), don't hang
      }
      // no fence needed: CACHED -> write-once ring (fresh-by-construction);
      // !CACHED -> sc1 loads bypass L1/L2
    }
    __syncthreads();   // A: arrival observed -> all waves may read h_t

    const int slotR = CACHED ? t       : (t & 1);
    const int slotW = CACHED ? (t + 1) : ((t + 1) & 1);
    unsigned short* hWr = hRing + (size_t)slotW * (BATCH * DL);
    float* out_t = out + (size_t)t * (BATCH * DL);

    // ---- pre-issue all 32 h loads (16B each, stride 64B) ----
    u32x4 hv[32];
    const unsigned short* hbase = hRing + (size_t)slotR * (BATCH * DL) + hOff;
    if constexpr (CACHED){
      LOADHC( 0,"0")    LOADHC( 1,"64")   LOADHC( 2,"128")  LOADHC( 3,"192")
      LOADHC( 4,"256")  LOADHC( 5,"320")  LOADHC( 6,"384")  LOADHC( 7,"448")
      LOADHC( 8,"512")  LOADHC( 9,"576")  LOADHC(10,"640")  LOADHC(11,"704")
      LOADHC(12,"768")  LOADHC(13,"832")  LOADHC(14,"896")  LOADHC(15,"960")
      LOADHC(16,"1024") LOADHC(17,"1088") LOADHC(18,"1152") LOADHC(19,"1216")
      LOADHC(20,"1280") LOADHC(21,"1344") LOADHC(22,"1408") LOADHC(23,"1472")
      LOADHC(24,"1536") LOADHC(25,"1600") LOADHC(26,"1664") LOADHC(27,"1728")
      LOADHC(28,"1792") LOADHC(29,"1856") LOADHC(30,"1920") LOADHC(31,"1984")
    } else {
      LOADHU( 0,"0")    LOADHU( 1,"64")   LOADHU( 2,"128")  LOADHU( 3,"192")
      LOADHU( 4,"256")  LOADHU( 5,"320")  LOADHU( 6,"384")  LOADHU( 7,"448")
      LOADHU( 8,"512")  LOADHU( 9,"576")  LOADHU(10,"640")  LOADHU(11,"704")
      LOADHU(12,"768")  LOADHU(13,"832")  LOADHU(14,"896")  LOADHU(15,"960")
      LOADHU(16,"1024") LOADHU(17,"1088") LOADHU(18,"1152") LOADHU(19,"1216")
      LOADHU(20,"1280") LOADHU(21,"1344") LOADHU(22,"1408") LOADHU(23,"1472")
      LOADHU(24,"1536") LOADHU(25,"1600") LOADHU(26,"1664") LOADHU(27,"1728")
      LOADHU(28,"1792") LOADHU(29,"1856") LOADHU(30,"1920") LOADHU(31,"1984")
    }
    asm volatile("s_waitcnt vmcnt(0)" ::: "memory");
    __builtin_amdgcn_sched_barrier(0);

    // ---- h-part: 2-term bf16 over K=1024, 4 chains ----
#pragma unroll
    for (int kc = 0; kc < NKC_H; kc += 4){
      HSTEP2(kc, acc0) HSTEP2(kc + 1, acc1) HSTEP2(kc + 2, acc2) HSTEP2(kc + 3, acc3)
    }
    f32x4 acc = (acc0 + acc1) + (acc2 + acc3);

    // ---- epilogue: gather f/i/c/o via shfl, gates, stage h/out into LDS ----
    float creg[4] = {cr0, cr1, cr2, cr3};
#pragma unroll
    for (int r = 0; r < 4; r++){
      float v = acc[r] + bias;
      float vF = __shfl(v, srcBase);
      float vI = __shfl(v, srcBase + 4);
      float vC = __shfl(v, srcBase + 8);
      float vO = __shfl(v, srcBase + 12);
      if (g == 0){
        int b = (w << 4) | (kg << 2) | r;
        float ft = fast_sigmoid(vF);
        float it = fast_sigmoid(vI);
        float gt = fast_tanh(vC);
        float ot = fast_sigmoid(vO);
        float cn = ft * creg[r] + it * gt;
        creg[r] = cn;
        float hn = ot * fast_tanh(cn);
        int si = (b << 2) | (lc & 3);
        stage_h[si] = f2bf(hn);
        stage_o[si] = hn;
      }
    }
    cr0 = creg[0]; cr1 = creg[1]; cr2 = creg[2]; cr3 = creg[3];

    __syncthreads();   // B: staging visible to wave 0

    // ---- wave 0: coalesced publish (ring sc0sc1 + out plain), drain, arrive ----
    if (w == 0){
      u32x2  hv2 = *(const u32x2*)&stage_h[lane << 2];   // 8B = one row's 4 cols
      f32x4  ov  = *(const f32x4*)&stage_o[lane << 2];
      *(float4*)(out_t + lane * DL + (bk << 2)) = *(const float4*)&ov;
      unsigned short* hdst = hWr + lane * DL + (bk << 2);
      asm volatile("global_store_dwordx2 %0, %1, off sc0 sc1"
                   :: "v"(hdst), "v"(hv2) : "memory");
      asm volatile("s_waitcnt vmcnt(0)" ::: "memory");
      __builtin_amdgcn_sched_barrier(0);
      if (tid == 0)
        __hip_atomic_fetch_add(bar, 1u, __ATOMIC_RELAXED, __HIP_MEMORY_SCOPE_AGENT);
    }

    // ---- overlap: x-part MFMAs for step t+1 (xe independent of h) ----
    acc0 = (f32x4){0.f,0.f,0.f,0.f}; acc1 = (f32x4){0.f,0.f,0.f,0.f};
    acc2 = (f32x4){0.f,0.f,0.f,0.f}; acc3 = (f32x4){0.f,0.f,0.f,0.f};
    if (t + 1 < T_STEPS){
      const unsigned short* xRow = xe + (size_t)(t + 1) * BATCH * DI + xOff;
#pragma unroll
      for (int kc = 0; kc < 16; kc += 4){
        XSTEP(kc, acc0) XSTEP(kc + 1, acc1) XSTEP(kc + 2, acc2) XSTEP(kc + 3, acc3)
      }
    }
  }
#undef XSTEP
#undef HSTEP2
#undef LOADHC
#undef LOADHU
}

extern "C" void kernel_launch(void* const* d_in, const int* in_sizes, int n_in,
                              void* d_out, int out_size, void* d_ws, size_t ws_size,
                              hipStream_t stream){
  const int*   X   = (const int*)d_in[0];
  const float* h0  = (const float*)d_in[1];
  const float* emb = (const float*)d_in[2];
  const float* Wf  = (const float*)d_in[3];
  const float* bf_ = (const float*)d_in[4];
  const float* Wi  = (const float*)d_in[5];
  const float* bi_ = (const float*)d_in[6];
  const float* Wc  = (const float*)d_in[7];
  const float* bc_ = (const float*)d_in[8];
  const float* Wo  = (const float*)d_in[9];
  const float* bo_ = (const float*)d_in[10];
  float* out = (float*)d_out;

  const size_t SLOT = (size_t)BATCH * DL;            // ring slot elems (bf16)
  const size_t base_need =
      sizeof(unsigned short) * ((size_t)T_STEPS * BATCH * DI        // xe
                              + (size_t)256 * NKC * 512             // W_hi
                              + (size_t)256 * NKC_H * 512)          // W_lo
    + sizeof(float) * 4096                                           // bias
    + sizeof(unsigned int) * 8 * FPAD + 4096;                        // bar + slack
  const size_t ring_full = sizeof(unsigned short) * SLOT * (size_t)(T_STEPS + 1);
  const bool cached = ws_size >= base_need + ring_full;
  const size_t ring_elems = cached ? SLOT * (size_t)(T_STEPS + 1) : SLOT * 2;

  char* ws = (char*)d_ws;
  size_t off = 0;
  auto alloc = [&](size_t bytes) -> void* {
    void* p = ws + off;
    off = (off + bytes + 255) & ~((size_t)255);
    return p;
  };
  unsigned short* xe        = (unsigned short*)alloc(sizeof(unsigned short) * (size_t)T_STEPS * BATCH * DI);
  unsigned short* W_hi      = (unsigned short*)alloc(sizeof(unsigned short) * (size_t)256 * NKC * 512);
  unsigned short* W_lo      = (unsigned short*)alloc(sizeof(unsigned short) * (size_t)256 * NKC_H * 512);
  unsigned short* hRing     = (unsigned short*)alloc(sizeof(unsigned short) * ring_elems);
  float*          bias_pack = (float*)alloc(sizeof(float) * 4096);
  unsigned int*   bar       = (unsigned int*)alloc(sizeof(unsigned int) * 8 * FPAD);
  (void)in_sizes; (void)n_in; (void)out_size;

  static bool attr_set = false;
  if (!attr_set){
    hipFuncSetAttribute((const void*)lstm_persist<true>,
                        hipFuncAttributeMaxDynamicSharedMemorySize, 160 * 1024);
    hipFuncSetAttribute((const void*)lstm_persist<false>,
                        hipFuncAttributeMaxDynamicSharedMemorySize, 160 * 1024);
    attr_set = true;
  }

  hipLaunchKernelGGL(prep_xe, dim3(8192), dim3(256), 0, stream, X, emb, xe);
  hipLaunchKernelGGL(prep_w,  dim3(3072), dim3(256), 0, stream, Wf, Wi, Wc, Wo, W_hi, W_lo);
  hipLaunchKernelGGL(prep_h,  dim3(256),  dim3(256), 0, stream, h0, bf_, bi_, bc_, bo_,
                     hRing, bias_pack, bar);
  if (cached)
    hipLaunchKernelGGL((lstm_persist<true>),  dim3(NBLK), dim3(NTHR), 80 * 1024, stream,
                       xe, W_hi, W_lo, hRing, bias_pack, out, bar);
  else
    hipLaunchKernelGGL((lstm_persist<false>), dim3(NBLK), dim3(NTHR), 80 * 1024, stream,
                       xe, W_hi, W_lo, hRing, bias_pack, out, bar);
}

// Round 14
// 4272.106 us; speedup vs baseline: 1.1481x; 1.1481x over previous
//
#include <hip/hip_runtime.h>

// LSTM on MI355X — persistent kernel, round 13.
// Base = R11 (best 4329us). ONE mechanism change: detection = 8 SPREAD relaxed
// agent fetch_add counters (counter bk&7; <=32 RMWs/line, below R12's 256-deep
// serialization knee) polled directly by consumers (64 lanes cover 8 lines in
// one memory round; done when all >= 32*t). Chain: drain -> add -> detect
// (2 links, was 4). Aggregator wave deleted (NTHR=256). Everything else
// byte-identical to R11. absmax canary: 0.001953125.

namespace {
constexpr int T_STEPS = 512;
constexpr int BATCH   = 64;
constexpr int DI      = 512;
constexpr int DL      = 1024;
constexpr int NKC     = 48;   // K=1536 in chunks of 32
constexpr int NKC_H   = 32;   // h-part chunks (K=1024)
constexpr int NBLK    = 256;  // grid == CU count, 1 block/CU resident
constexpr int NTHR    = 256;  // 4 compute waves
constexpr int FPAD    = 32;   // uints per counter slot (128 B padding)
}

typedef __attribute__((ext_vector_type(8))) short bf16x8;
typedef __attribute__((ext_vector_type(8))) unsigned short u16x8;
typedef __attribute__((ext_vector_type(4))) float f32x4;
typedef __attribute__((ext_vector_type(4))) unsigned int u32x4;
typedef __attribute__((ext_vector_type(2))) unsigned int u32x2;

__device__ __forceinline__ unsigned short f2bf(float x){
  unsigned int u = __float_as_uint(x);
  return (unsigned short)((u + 0x7FFFu + ((u >> 16) & 1u)) >> 16);
}
__device__ __forceinline__ float bf2f(unsigned short b){
  return __uint_as_float(((unsigned int)b) << 16);
}
__device__ __forceinline__ float fast_sigmoid(float v){
  return __fdividef(1.f, 1.f + __expf(-v));
}
__device__ __forceinline__ float fast_tanh(float v){
  v = fminf(fmaxf(v, -15.f), 15.f);
  float t = __expf(2.f * v);
  return __fdividef(t - 1.f, t + 1.f);
}

// ---------------- prep: embeddings -> bf16 [T*B][DI] ----------------
__global__ void prep_xe(const int* __restrict__ X, const float* __restrict__ emb,
                        unsigned short* __restrict__ xe){
  int i = blockIdx.x * blockDim.x + threadIdx.x;
  const int total = T_STEPS * BATCH * DI / 8;
  if (i >= total) return;
  int row = i >> 6;
  int seg = i & 63;
  int tok = X[row];
  const float* src = emb + (long long)tok * DI + seg * 8;
  float4 v0 = *(const float4*)src;
  float4 v1 = *(const float4*)(src + 4);
  u16x8 o;
  o[0]=f2bf(v0.x); o[1]=f2bf(v0.y); o[2]=f2bf(v0.z); o[3]=f2bf(v0.w);
  o[4]=f2bf(v1.x); o[5]=f2bf(v1.y); o[6]=f2bf(v1.z); o[7]=f2bf(v1.w);
  *(u16x8*)(xe + (long long)row * DI + seg * 8) = o;
}

// ---------------- prep: pack W into MFMA B-fragment layout, hi/lo ----------------
__global__ void prep_w(const float* __restrict__ Wf, const float* __restrict__ Wi,
                       const float* __restrict__ Wc, const float* __restrict__ Wo,
                       unsigned short* __restrict__ W_hi, unsigned short* __restrict__ W_lo){
  int idx = blockIdx.x * blockDim.x + threadIdx.x;
  if (idx >= 256 * NKC * 64) return;
  int lane = idx & 63;
  int kc   = (idx >> 6) % NKC;
  int bk   = idx / (64 * NKC);
  int lc = lane & 15, kg = lane >> 4;
  int g  = lc >> 2;
  int jl = bk * 4 + (lc & 3);
  const float* Wg = (g == 0) ? Wf : ((g == 1) ? Wi : ((g == 2) ? Wc : Wo));
  int kbase = kc * 32 + kg * 8;
  u16x8 hi, lo;
#pragma unroll
  for (int j = 0; j < 8; j++){
    float wv = Wg[(long long)(kbase + j) * DL + jl];
    unsigned short h = f2bf(wv);
    hi[j] = h;
    lo[j] = f2bf(wv - bf2f(h));
  }
  *(u16x8*)(W_hi + ((long long)(bk * NKC + kc) * 64 + lane) * 8) = hi;
  if (kc < NKC_H)
    *(u16x8*)(W_lo + ((long long)(bk * NKC_H + kc) * 64 + lane) * 8) = lo;
}

// ---------------- prep: h0 -> ring slot 0 (bf16), bias pack, counters zero ----------------
__global__ void prep_h(const float* __restrict__ h0,
                       const float* __restrict__ bf_, const float* __restrict__ bi_,
                       const float* __restrict__ bc_, const float* __restrict__ bo_,
                       unsigned short* __restrict__ hRing,
                       float* __restrict__ bias_pack, unsigned int* __restrict__ bar){
  int i = blockIdx.x * blockDim.x + threadIdx.x;
  if (i < BATCH * DL) hRing[i] = f2bf(h0[i]);      // slot 0 = h_0
  if (i < 4096){
    int r = i & 3, g = (i >> 2) & 3, bk = i >> 4;
    const float* bg = (g == 0) ? bf_ : ((g == 1) ? bi_ : ((g == 2) ? bc_ : bo_));
    bias_pack[i] = bg[bk * 4 + r];
  }
  if (i < 8 * FPAD) bar[i] = 0u;                   // 8 counter lines
}

// ---------------- persistent LSTM: all 512 steps in one kernel ----------------
// CACHED=true : ring depth T+1 (write-once), consumer loads plain cached.
// CACHED=false: ring depth 2 (double buffer),  consumer loads sc0 sc1 (=R6).
template<bool CACHED>
__launch_bounds__(NTHR, 1)
__global__ void lstm_persist(const unsigned short* __restrict__ xe,
                             const unsigned short* __restrict__ W_hi,
                             const unsigned short* __restrict__ W_lo,
                             unsigned short* __restrict__ hRing,
                             const float* __restrict__ bias_pack,
                             float* __restrict__ out,
                             unsigned int* __restrict__ bar){
  extern __shared__ unsigned short lds[];
  unsigned short* lds_hi = lds;              // NKC  *512 elems (48 KB)
  unsigned short* lds_lo = lds + NKC * 512;  // NKC_H*512 elems (32 KB)
  __shared__ unsigned short stage_h[BATCH * 4];  // bf16 h slice [64 rows][4 cols]
  __shared__ float          stage_o[BATCH * 4];  // out slice
  const int tid  = threadIdx.x;
  const int bk   = blockIdx.x;
  const int w    = tid >> 6;
  const int lane = tid & 63;

  // stage W once for the whole run
  const uint4* srcHi = (const uint4*)(W_hi + (size_t)bk * NKC * 512);
  uint4* dHi = (uint4*)lds_hi;
  for (int i = tid; i < 3072; i += NTHR) dHi[i] = srcHi[i];
  const uint4* srcLo = (const uint4*)(W_lo + (size_t)bk * NKC_H * 512);
  uint4* dLo = (uint4*)lds_lo;
  for (int i = tid; i < 2048; i += NTHR) dLo[i] = srcLo[i];
  __syncthreads();

  const int lc = lane & 15;
  const int kg = lane >> 4;
  const int g  = lc >> 2;
  const int rowb = (w << 4) + lc;
  const float bias = bias_pack[bk * 16 + lc];
  const int srcBase = (lane & 48) | (lc & 3);
  const int hOff = rowb * DL + kg * 8;     // u16 elements
  const int xOff = rowb * DI + kg * 8;
  unsigned int* myCtr = bar + (bk & 7) * FPAD;
  unsigned int* pollp = bar + (lane & 7) * FPAD;   // 64 lanes cover 8 lines
  float cr0 = 0.f, cr1 = 0.f, cr2 = 0.f, cr3 = 0.f;

  f32x4 acc0 = {0.f,0.f,0.f,0.f}, acc1 = {0.f,0.f,0.f,0.f};
  f32x4 acc2 = {0.f,0.f,0.f,0.f}, acc3 = {0.f,0.f,0.f,0.f};

#define XSTEP(KC, ACC) {                                                        \
    bf16x8 ax = *(const bf16x8*)(xRow + (KC) * 32);                             \
    bf16x8 bh = *(const bf16x8*)(lds_hi + (NKC_H + (KC)) * 512 + lane * 8);     \
    ACC = __builtin_amdgcn_mfma_f32_16x16x32_bf16(ax, bh, ACC, 0, 0, 0); }
#define HSTEP2(KC, ACC) {                                                       \
    bf16x8 ah = *(const bf16x8*)&hv[KC];                                        \
    bf16x8 bh = *(const bf16x8*)(lds_hi + (KC) * 512 + lane * 8);               \
    bf16x8 bl = *(const bf16x8*)(lds_lo + (KC) * 512 + lane * 8);               \
    ACC = __builtin_amdgcn_mfma_f32_16x16x32_bf16(ah, bh, ACC, 0, 0, 0);        \
    ACC = __builtin_amdgcn_mfma_f32_16x16x32_bf16(ah, bl, ACC, 0, 0, 0); }
#define LOADHC(I, OFFSTR)                                                       \
    asm volatile("global_load_dwordx4 %0, %1, off offset:" OFFSTR               \
                 : "=v"(hv[I]) : "v"(hbase));
#define LOADHU(I, OFFSTR)                                                       \
    asm volatile("global_load_dwordx4 %0, %1, off offset:" OFFSTR " sc0 sc1"    \
                 : "=v"(hv[I]) : "v"(hbase));

  // x-part for step 0
  {
    const unsigned short* xRow = xe + xOff;
#pragma unroll
    for (int kc = 0; kc < 16; kc += 4){
      XSTEP(kc, acc0) XSTEP(kc + 1, acc1) XSTEP(kc + 2, acc2) XSTEP(kc + 3, acc3)
    }
  }

#pragma unroll 1
  for (int t = 0; t < T_STEPS; ++t){
    // ---- wait: all 8 counters >= 32*t (w0 polls; 1 memory round/poll) ----
    if (t > 0 && w == 0){
      const unsigned tgt = 32u * (unsigned)t;
      int spin = 0;
      for (;;){
        unsigned v = __hip_atomic_load(pollp, __ATOMIC_RELAXED, __HIP_MEMORY_SCOPE_AGENT);
        if (__all((v >= tgt) ? 1 : 0)) break;
        __builtin_amdgcn_s_sleep(2);
        if (++spin > (1 << 16)) break;   // bail loud (absmax), don't hang
      }
      // no fence needed: CACHED -> write-once ring (fresh-by-construction);
      // !CACHED -> sc1 loads bypass L1/L2
    }
    __syncthreads();   // A: arrivals observed -> all waves may read h_t

    const int slotR = CACHED ? t       : (t & 1);
    const int slotW = CACHED ? (t + 1) : ((t + 1) & 1);
    unsigned short* hWr = hRing + (size_t)slotW * (BATCH * DL);
    float* out_t = out + (size_t)t * (BATCH * DL);

    // ---- pre-issue all 32 h loads (16B each, stride 64B) ----
    u32x4 hv[32];
    const unsigned short* hbase = hRing + (size_t)slotR * (BATCH * DL) + hOff;
    if constexpr (CACHED){
      LOADHC( 0,"0")    LOADHC( 1,"64")   LOADHC( 2,"128")  LOADHC( 3,"192")
      LOADHC( 4,"256")  LOADHC( 5,"320")  LOADHC( 6,"384")  LOADHC( 7,"448")
      LOADHC( 8,"512")  LOADHC( 9,"576")  LOADHC(10,"640")  LOADHC(11,"704")
      LOADHC(12,"768")  LOADHC(13,"832")  LOADHC(14,"896")  LOADHC(15,"960")
      LOADHC(16,"1024") LOADHC(17,"1088") LOADHC(18,"1152") LOADHC(19,"1216")
      LOADHC(20,"1280") LOADHC(21,"1344") LOADHC(22,"1408") LOADHC(23,"1472")
      LOADHC(24,"1536") LOADHC(25,"1600") LOADHC(26,"1664") LOADHC(27,"1728")
      LOADHC(28,"1792") LOADHC(29,"1856") LOADHC(30,"1920") LOADHC(31,"1984")
    } else {
      LOADHU( 0,"0")    LOADHU( 1,"64")   LOADHU( 2,"128")  LOADHU( 3,"192")
      LOADHU( 4,"256")  LOADHU( 5,"320")  LOADHU( 6,"384")  LOADHU( 7,"448")
      LOADHU( 8,"512")  LOADHU( 9,"576")  LOADHU(10,"640")  LOADHU(11,"704")
      LOADHU(12,"768")  LOADHU(13,"832")  LOADHU(14,"896")  LOADHU(15,"960")
      LOADHU(16,"1024") LOADHU(17,"1088") LOADHU(18,"1152") LOADHU(19,"1216")
      LOADHU(20,"1280") LOADHU(21,"1344") LOADHU(22,"1408") LOADHU(23,"1472")
      LOADHU(24,"1536") LOADHU(25,"1600") LOADHU(26,"1664") LOADHU(27,"1728")
      LOADHU(28,"1792") LOADHU(29,"1856") LOADHU(30,"1920") LOADHU(31,"1984")
    }
    asm volatile("s_waitcnt vmcnt(0)" ::: "memory");
    __builtin_amdgcn_sched_barrier(0);

    // ---- h-part: 2-term bf16 over K=1024, 4 chains ----
#pragma unroll
    for (int kc = 0; kc < NKC_H; kc += 4){
      HSTEP2(kc, acc0) HSTEP2(kc + 1, acc1) HSTEP2(kc + 2, acc2) HSTEP2(kc + 3, acc3)
    }
    f32x4 acc = (acc0 + acc1) + (acc2 + acc3);

    // ---- epilogue: gather f/i/c/o via shfl, gates, stage h/out into LDS ----
    float creg[4] = {cr0, cr1, cr2, cr3};
#pragma unroll
    for (int r = 0; r < 4; r++){
      float v = acc[r] + bias;
      float vF = __shfl(v, srcBase);
      float vI = __shfl(v, srcBase + 4);
      float vC = __shfl(v, srcBase + 8);
      float vO = __shfl(v, srcBase + 12);
      if (g == 0){
        int b = (w << 4) | (kg << 2) | r;
        float ft = fast_sigmoid(vF);
        float it = fast_sigmoid(vI);
        float gt = fast_tanh(vC);
        float ot = fast_sigmoid(vO);
        float cn = ft * creg[r] + it * gt;
        creg[r] = cn;
        float hn = ot * fast_tanh(cn);
        int si = (b << 2) | (lc & 3);
        stage_h[si] = f2bf(hn);
        stage_o[si] = hn;
      }
    }
    cr0 = creg[0]; cr1 = creg[1]; cr2 = creg[2]; cr3 = creg[3];

    __syncthreads();   // B: staging visible to wave 0

    // ---- wave 0: coalesced publish (ring sc0sc1 + out plain), drain, add ----
    if (w == 0){
      u32x2  hv2 = *(const u32x2*)&stage_h[lane << 2];   // 8B = one row's 4 cols
      f32x4  ov  = *(const f32x4*)&stage_o[lane << 2];
      *(float4*)(out_t + lane * DL + (bk << 2)) = *(const float4*)&ov;
      unsigned short* hdst = hWr + lane * DL + (bk << 2);
      asm volatile("global_store_dwordx2 %0, %1, off sc0 sc1"
                   :: "v"(hdst), "v"(hv2) : "memory");
      asm volatile("s_waitcnt vmcnt(0)" ::: "memory");
      __builtin_amdgcn_sched_barrier(0);
      if (tid == 0)
        __hip_atomic_fetch_add(myCtr, 1u, __ATOMIC_RELAXED, __HIP_MEMORY_SCOPE_AGENT);
    }

    // ---- overlap: x-part MFMAs for step t+1 (xe independent of h) ----
    acc0 = (f32x4){0.f,0.f,0.f,0.f}; acc1 = (f32x4){0.f,0.f,0.f,0.f};
    acc2 = (f32x4){0.f,0.f,0.f,0.f}; acc3 = (f32x4){0.f,0.f,0.f,0.f};
    if (t + 1 < T_STEPS){
      const unsigned short* xRow = xe + (size_t)(t + 1) * BATCH * DI + xOff;
#pragma unroll
      for (int kc = 0; kc < 16; kc += 4){
        XSTEP(kc, acc0) XSTEP(kc + 1, acc1) XSTEP(kc + 2, acc2) XSTEP(kc + 3, acc3)
      }
    }
  }
#undef XSTEP
#undef HSTEP2
#undef LOADHC
#undef LOADHU
}

extern "C" void kernel_launch(void* const* d_in, const int* in_sizes, int n_in,
                              void* d_out, int out_size, void* d_ws, size_t ws_size,
                              hipStream_t stream){
  const int*   X   = (const int*)d_in[0];
  const float* h0  = (const float*)d_in[1];
  const float* emb = (const float*)d_in[2];
  const float* Wf  = (const float*)d_in[3];
  const float* bf_ = (const float*)d_in[4];
  const float* Wi  = (const float*)d_in[5];
  const float* bi_ = (const float*)d_in[6];
  const float* Wc  = (const float*)d_in[7];
  const float* bc_ = (const float*)d_in[8];
  const float* Wo  = (const float*)d_in[9];
  const float* bo_ = (const float*)d_in[10];
  float* out = (float*)d_out;

  const size_t SLOT = (size_t)BATCH * DL;            // ring slot elems (bf16)
  const size_t base_need =
      sizeof(unsigned short) * ((size_t)T_STEPS * BATCH * DI        // xe
                              + (size_t)256 * NKC * 512             // W_hi
                              + (size_t)256 * NKC_H * 512)          // W_lo
    + sizeof(float) * 4096                                           // bias
    + sizeof(unsigned int) * 8 * FPAD + 4096;                        // bar + slack
  const size_t ring_full = sizeof(unsigned short) * SLOT * (size_t)(T_STEPS + 1);
  const bool cached = ws_size >= base_need + ring_full;
  const size_t ring_elems = cached ? SLOT * (size_t)(T_STEPS + 1) : SLOT * 2;

  char* ws = (char*)d_ws;
  size_t off = 0;
  auto alloc = [&](size_t bytes) -> void* {
    void* p = ws + off;
    off = (off + bytes + 255) & ~((size_t)255);
    return p;
  };
  unsigned short* xe        = (unsigned short*)alloc(sizeof(unsigned short) * (size_t)T_STEPS * BATCH * DI);
  unsigned short* W_hi      = (unsigned short*)alloc(sizeof(unsigned short) * (size_t)256 * NKC * 512);
  unsigned short* W_lo      = (unsigned short*)alloc(sizeof(unsigned short) * (size_t)256 * NKC_H * 512);
  unsigned short* hRing     = (unsigned short*)alloc(sizeof(unsigned short) * ring_elems);
  float*          bias_pack = (float*)alloc(sizeof(float) * 4096);
  unsigned int*   bar       = (unsigned int*)alloc(sizeof(unsigned int) * 8 * FPAD);
  (void)in_sizes; (void)n_in; (void)out_size;

  static bool attr_set = false;
  if (!attr_set){
    hipFuncSetAttribute((const void*)lstm_persist<true>,
                        hipFuncAttributeMaxDynamicSharedMemorySize, 160 * 1024);
    hipFuncSetAttribute((const void*)lstm_persist<false>,
                        hipFuncAttributeMaxDynamicSharedMemorySize, 160 * 1024);
    attr_set = true;
  }

  hipLaunchKernelGGL(prep_xe, dim3(8192), dim3(256), 0, stream, X, emb, xe);
  hipLaunchKernelGGL(prep_w,  dim3(3072), dim3(256), 0, stream, Wf, Wi, Wc, Wo, W_hi, W_lo);
  hipLaunchKernelGGL(prep_h,  dim3(256),  dim3(256), 0, stream, h0, bf_, bi_, bc_, bo_,
                     hRing, bias_pack, bar);
  if (cached)
    hipLaunchKernelGGL((lstm_persist<true>),  dim3(NBLK), dim3(NTHR), 80 * 1024, stream,
                       xe, W_hi, W_lo, hRing, bias_pack, out, bar);
  else
    hipLaunchKernelGGL((lstm_persist<false>), dim3(NBLK), dim3(NTHR), 80 * 1024, stream,
                       xe, W_hi, W_lo, hRing, bias_pack, out, bar);
}